// Round 4
// baseline (418.648 us; speedup 1.0000x reference)
//
#include <hip/hip_runtime.h>
#include <cstdint>
#include <cstddef>

#define B_ 64
#define P_ 24564
#define C_ 21
#define N_ 16
#define NPB_ 24          // kA blocks per batch: 24*1024 >= P_
#define THRESH_ 0.5f

// ---------------------------------------------------------------- helpers

__device__ inline unsigned long long shfl_down_u64(unsigned long long v, int off) {
    unsigned lo = (unsigned)v, hi = (unsigned)(v >> 32);
    lo = __shfl_down(lo, off);
    hi = __shfl_down(hi, off);
    return ((unsigned long long)hi << 32) | lo;
}

// smooth-L1 of (loc row - encoded(truth, prior)), summed over 4 coords
__device__ inline float sl1_encode(float4 ld, float4 pr,
                                   float tx1, float ty1, float tx2, float ty2) {
    float gcx = ((tx1 + tx2) * 0.5f - pr.x) / (0.1f * pr.z);
    float gcy = ((ty1 + ty2) * 0.5f - pr.y) / (0.1f * pr.w);
    float gw  = logf((tx2 - tx1) / pr.z) / 0.2f;
    float gh  = logf((ty2 - ty1) / pr.w) / 0.2f;
    float g[4] = {gcx, gcy, gw, gh};
    float l[4] = {ld.x, ld.y, ld.z, ld.w};
    float s = 0.0f;
#pragma unroll
    for (int i = 0; i < 4; i++) {
        float d = l[i] - g[i];
        float ad = fabsf(d);
        s += (ad < 1.0f) ? 0.5f * d * d : ad - 0.5f;
    }
    return s;
}

// ---------------------------------------------------------------- kernels

// kA: fused match + baseline loss (no override) + per-block best-prior
// argmax partials. Thread owns 4 consecutive priors (21 float4 conf loads,
// deep MLP). No global atomics.
__global__ __launch_bounds__(256) void
kA_fused(const float* __restrict__ loc,
         const float* __restrict__ conf,
         const float* __restrict__ priors,
         const float* __restrict__ truths,
         const int* __restrict__ labels,
         float* __restrict__ mine,
         float* __restrict__ part_ll,
         float* __restrict__ part_pce,
         int* __restrict__ part_np,
         unsigned long long* __restrict__ part_key) {
    int b = blockIdx.y, bx = blockIdx.x, t = threadIdx.x;
    __shared__ float tr[N_ * 4];
    __shared__ int lb[N_];
    __shared__ unsigned long long tmax[N_];
    if (t < N_ * 4) tr[t] = truths[b * N_ * 4 + t];
    if (t < N_) { lb[t] = labels[b * N_ + t]; tmax[t] = 0ull; }
    __syncthreads();

    int p0 = bx * 1024 + 4 * t;
    bool valid = p0 < P_;            // P_ % 4 == 0: all-or-nothing per thread
    int lane = t & 63;

    // conf rows early (independent of IoU work -> deep in flight)
    float c[84];
    if (valid) {
        const float4* src = (const float4*)(conf + ((size_t)b * P_ + (size_t)bx * 1024) * C_);
        float4* cv = (float4*)c;
#pragma unroll
        for (int i = 0; i < 21; i++) cv[i] = src[t * 21 + i];
    }

    float4 pr[4];
#pragma unroll
    for (int r = 0; r < 4; r++)
        pr[r] = valid ? ((const float4*)priors)[p0 + r]
                      : make_float4(0.5f, 0.5f, 0.1f, 0.1f);

    float px1[4], py1[4], px2[4], py2[4], ap[4];
#pragma unroll
    for (int r = 0; r < 4; r++) {
        px1[r] = pr[r].x - pr[r].z * 0.5f; py1[r] = pr[r].y - pr[r].w * 0.5f;
        px2[r] = pr[r].x + pr[r].z * 0.5f; py2[r] = pr[r].y + pr[r].w * 0.5f;
        ap[r] = (px2[r] - px1[r]) * (py2[r] - py1[r]);
    }

    float best[4] = {-1.0f, -1.0f, -1.0f, -1.0f};
    int bn[4] = {0, 0, 0, 0};

#pragma unroll
    for (int n = 0; n < N_; n++) {
        float tx1 = tr[n * 4 + 0], ty1 = tr[n * 4 + 1];
        float tx2 = tr[n * 4 + 2], ty2 = tr[n * 4 + 3];
        float at = (tx2 - tx1) * (ty2 - ty1);
        float tbi = -1.0f;           // this thread's best iou for truth n
        int tbr = 0;
#pragma unroll
        for (int r = 0; r < 4; r++) {
            float lx = fmaxf(tx1, px1[r]), ly = fmaxf(ty1, py1[r]);
            float rx = fminf(tx2, px2[r]), ry = fminf(ty2, py2[r]);
            float w = fmaxf(rx - lx, 0.0f), h = fmaxf(ry - ly, 0.0f);
            float inter = w * h;
            float iou = inter / (at + ap[r] - inter);
            if (iou > best[r]) { best[r] = iou; bn[r] = n; }
            if (iou > tbi) { tbi = iou; tbr = r; }   // smallest r on ties
        }
        // wave-reduce argmax key for truth n (all 64 lanes active here)
        unsigned long long key = valid
            ? (((unsigned long long)__float_as_uint(tbi) << 32) |
               (unsigned)~(unsigned)(p0 + tbr))
            : 0ull;
        for (int off = 32; off; off >>= 1) {
            unsigned long long o = shfl_down_u64(key, off);
            key = (o > key) ? o : key;
        }
        if (lane == 0) atomicMax(&tmax[n], key);
    }

    // baseline loss (no override; corrections applied in kB)
    float ll = 0.0f, pce = 0.0f;
    int np = 0;
    if (valid) {
        float mv[4];
#pragma unroll
        for (int r = 0; r < 4; r++) {
            int bti = bn[r];
            int pos = (best[r] < THRESH_) ? 0 : 1;
            int cls = pos ? (lb[bti] + 1) : 0;

            float mx = -1e30f, g = 0.0f;
#pragma unroll
            for (int j = 0; j < C_; j++) {
                float x = c[21 * r + j];
                mx = fmaxf(mx, x);
                if (j == cls) g = x;
            }
            float s = 0.0f;
#pragma unroll
            for (int j = 0; j < C_; j++) s += expf(c[21 * r + j] - mx);
            float lca = mx + logf(s) - g;          // >= 0 always

            mv[r] = pos ? 0.0f : lca;
            if (pos) {
                np++;
                pce += lca;
                float4 ld = ((const float4*)loc)[(size_t)b * P_ + p0 + r];
                ll += sl1_encode(ld, pr[r], tr[bti * 4 + 0], tr[bti * 4 + 1],
                                 tr[bti * 4 + 2], tr[bti * 4 + 3]);
            }
        }
        *(float4*)(mine + (size_t)b * P_ + p0) = make_float4(mv[0], mv[1], mv[2], mv[3]);
    }

    for (int off = 32; off; off >>= 1) {
        ll += __shfl_down(ll, off);
        pce += __shfl_down(pce, off);
        np += __shfl_down(np, off);
    }
    __shared__ float sll[4], spc[4];
    __shared__ int snp[4];
    int wid = t >> 6;
    if (lane == 0) { sll[wid] = ll; spc[wid] = pce; snp[wid] = np; }
    __syncthreads();
    if (t == 0) {
        float a = 0.0f, cc = 0.0f;
        int q = 0;
        for (int i = 0; i < 4; i++) { a += sll[i]; cc += spc[i]; q += snp[i]; }
        part_ll[b * NPB_ + bx] = a;
        part_pce[b * NPB_ + bx] = cc;
        part_np[b * NPB_ + bx] = q;
    }
    if (t < N_) part_key[(size_t)(b * NPB_ + bx) * N_ + t] = tmax[t];
}

// kB: one block per batch. Reduce argmax partials -> bpi; apply exact
// override deltas for the <=16 affected priors; top-k via radix select with
// ballot-aggregated histogram atomics (match_any emulation).
__global__ __launch_bounds__(1024) void
kB_batch(const float* __restrict__ loc,
         const float* __restrict__ conf,
         const float* __restrict__ priors,
         const float* __restrict__ truths,
         const int* __restrict__ labels,
         const float* __restrict__ mine,
         const float* __restrict__ part_ll,
         const float* __restrict__ part_pce,
         const int* __restrict__ part_np,
         const unsigned long long* __restrict__ part_key,
         double* __restrict__ bll,
         double* __restrict__ bpc,
         int* __restrict__ bnp) {
    int b = blockIdx.x, t = threadIdx.x, wid = t >> 6, lane = t & 63;
    __shared__ float tr[N_ * 4];
    __shared__ int lb[N_];
    __shared__ int sp[N_];
    __shared__ int op[N_], on_[N_];
    __shared__ int sm;
    __shared__ float sdll, sdpce, sll_s, spc_s;
    __shared__ int sdnp, snp_s;
    __shared__ unsigned cnt[16 * 256];
    __shared__ unsigned spfx;
    __shared__ int skrem;
    __shared__ float wsum[16];

    if (t < N_ * 4) tr[t] = truths[b * N_ * 4 + t];
    if (t < N_) lb[t] = labels[b * N_ + t];
    if (t == 0) { sdll = 0.f; sdpce = 0.f; sdnp = 0; sll_s = 0.f; spc_s = 0.f; snp_s = 0; }
    if (t < N_) {                                  // phase 1: bpi reduce
        unsigned long long best = 0ull;
        for (int i = 0; i < NPB_; i++) {
            unsigned long long k = part_key[(size_t)(b * NPB_ + i) * N_ + t];
            best = (k > best) ? k : best;
        }
        sp[t] = (int)~(unsigned)(best & 0xFFFFFFFFull);
    }
    __syncthreads();
    if (t < NPB_) {                                // partial-sum gather
        atomicAdd(&sll_s, part_ll[b * NPB_ + t]);
        atomicAdd(&spc_s, part_pce[b * NPB_ + t]);
        atomicAdd(&snp_s, part_np[b * NPB_ + t]);
    }
    if (t == 0) {                                  // phase 2: dedup, last n wins
        int m = 0;
        for (int n = 0; n < N_; n++) {
            int p = sp[n], j;
            for (j = 0; j < m; j++) if (op[j] == p) { on_[j] = n; break; }
            if (j == m) { op[m] = p; on_[m] = n; m++; }
        }
        sm = m;
    }
    __syncthreads();
    int m = sm;
    if (t < m) {                                   // phase 3: exact deltas
        int p = op[t], nf = on_[t];
        float4 pr = ((const float4*)priors)[p];
        float px1 = pr.x - pr.z * 0.5f, py1 = pr.y - pr.w * 0.5f;
        float px2 = pr.x + pr.z * 0.5f, py2 = pr.y + pr.w * 0.5f;
        float ap = (px2 - px1) * (py2 - py1);
        float best = -1.0f;
        int bti = 0;
        for (int n = 0; n < N_; n++) {
            float tx1 = tr[n * 4], ty1 = tr[n * 4 + 1];
            float tx2 = tr[n * 4 + 2], ty2 = tr[n * 4 + 3];
            float at = (tx2 - tx1) * (ty2 - ty1);
            float lx = fmaxf(tx1, px1), ly = fmaxf(ty1, py1);
            float rx = fminf(tx2, px2), ry = fminf(ty2, py2);
            float w = fmaxf(rx - lx, 0.0f), h = fmaxf(ry - ly, 0.0f);
            float inter = w * h;
            float iou = inter / (at + ap - inter);
            if (iou > best) { best = iou; bti = n; }
        }
        int pos_old = (best >= THRESH_) ? 1 : 0;
        const float* cp = conf + ((size_t)b * P_ + p) * C_;
        float x[C_];
        float mx = -1e30f;
        for (int j = 0; j < C_; j++) { x[j] = cp[j]; mx = fmaxf(mx, x[j]); }
        float s = 0.0f;
        for (int j = 0; j < C_; j++) s += expf(x[j] - mx);
        float lse = mx + logf(s);
        float4 ld = ((const float4*)loc)[(size_t)b * P_ + p];
        float dll = sl1_encode(ld, pr, tr[nf * 4], tr[nf * 4 + 1],
                               tr[nf * 4 + 2], tr[nf * 4 + 3]);
        float dpce = lse - x[lb[nf] + 1];
        int dnp = 1 - pos_old;
        if (pos_old) {
            dll -= sl1_encode(ld, pr, tr[bti * 4], tr[bti * 4 + 1],
                              tr[bti * 4 + 2], tr[bti * 4 + 3]);
            dpce -= lse - x[lb[bti] + 1];
        }
        atomicAdd(&sdll, dll);
        atomicAdd(&sdpce, dpce);
        atomicAdd(&sdnp, dnp);
    }
    __syncthreads();
    int np = snp_s + sdnp;
    int k = np * 3;
    if (k > P_ - 1) k = P_ - 1;
    if (t == 0) { spfx = 0u; skrem = k; }
    const float* v = mine + (size_t)b * P_;

    for (int pass = 0; pass < 4; pass++) {
        for (int i = t; i < 16 * 256; i += 1024) cnt[i] = 0u;
        __syncthreads();
        unsigned pf = spfx;
        unsigned pm = pass ? (0xFFFFFFFFu << (32 - 8 * pass)) : 0u;
        int shift = 24 - 8 * pass;
        for (int p = t; p < P_; p += 1024) {
            float xv = v[p];
            for (int j = 0; j < m; j++) if (p == op[j]) xv = 0.0f;  // override patch
            unsigned u = __float_as_uint(xv);
            if ((u & pm) == pf) {
                unsigned bin = (u >> shift) & 255u;
                // match_any emulation: one atomic per distinct bin per wave
                unsigned long long act = __ballot(1);
                unsigned long long eq = act;
#pragma unroll
                for (int bit = 0; bit < 8; bit++) {
                    unsigned long long bal = __ballot((bin >> bit) & 1);
                    eq &= ((bin >> bit) & 1) ? bal : ~bal;
                }
                if ((int)(__ffsll((long long)eq) - 1) == lane)
                    atomicAdd(&cnt[(wid << 8) + bin], (unsigned)__popcll(eq));
            }
        }
        __syncthreads();
        if (t < 256) {
            unsigned s2 = 0;
            for (int cc = 0; cc < 16; cc++) s2 += cnt[(cc << 8) + t];
            cnt[t] = s2;
        }
        __syncthreads();
        if (t == 0) {
            int kr = skrem;
            unsigned c2 = 0;
            int bin;
            for (bin = 255; bin >= 0; bin--) {
                if ((int)(c2 + cnt[bin]) >= kr) break;
                c2 += cnt[bin];
            }
            if (bin < 0) bin = 0;          // defensive
            skrem = kr - (int)c2;
            spfx = pf | ((unsigned)bin << shift);
        }
        __syncthreads();
    }

    unsigned thr = spfx;                   // exact k-th largest bit pattern
    float psum = 0.0f;
    for (int p = t; p < P_; p += 1024) {
        float xv = v[p];
        for (int j = 0; j < m; j++) if (p == op[j]) xv = 0.0f;
        if (__float_as_uint(xv) > thr) psum += xv;
    }
    for (int off = 32; off; off >>= 1) psum += __shfl_down(psum, off);
    if (lane == 0) wsum[wid] = psum;
    __syncthreads();
    if (t == 0) {
        float s2 = 0.0f;
        for (int i = 0; i < 16; i++) s2 += wsum[i];
        double tot = (double)s2 + (double)skrem * (double)__uint_as_float(thr);
        bll[b] = (double)(sll_s + sdll);
        bpc[b] = (double)(spc_s + sdpce) + tot;
        bnp[b] = np;
    }
}

// kC: final 64-wide reduce.
__global__ void kC_final(const double* __restrict__ bll,
                         const double* __restrict__ bpc,
                         const int* __restrict__ bnp,
                         float* __restrict__ out) {
    int t = threadIdx.x;  // 64 threads
    double a = bll[t], c = bpc[t];
    int n = bnp[t];
    for (int off = 32; off; off >>= 1) {
        a += __shfl_down(a, off);
        c += __shfl_down(c, off);
        n += __shfl_down(n, off);
    }
    if (t == 0) {
        double dn = (double)n;
        out[0] = (float)(a / dn);
        out[1] = (float)(c / dn);
    }
}

// ---------------------------------------------------------------- launch

extern "C" void kernel_launch(void* const* d_in, const int* in_sizes, int n_in,
                              void* d_out, int out_size, void* d_ws, size_t ws_size,
                              hipStream_t stream) {
    const float* loc    = (const float*)d_in[0];
    const float* conf   = (const float*)d_in[1];
    const float* priors = (const float*)d_in[2];
    const float* truths = (const float*)d_in[3];
    const int*   labels = (const int*)d_in[4];
    float* out = (float*)d_out;

    char* ws = (char*)d_ws;
    // layout:
    //   [0      .. 196608)  part_key: 1536*16 u64
    //   [196608 .. 202752)  part_ll:  1536 floats
    //   [202752 .. 208896)  part_pce: 1536 floats
    //   [208896 .. 215040)  part_np:  1536 ints
    //   [215040 .. 215552)  bll: 64 doubles
    //   [215552 .. 216064)  bpc: 64 doubles
    //   [216064 .. 216320)  bnp: 64 ints
    //   [262144 .. 6550528) mine: B*P floats
    unsigned long long* part_key = (unsigned long long*)(ws);
    float*  part_ll  = (float*)(ws + 196608);
    float*  part_pce = (float*)(ws + 202752);
    int*    part_np  = (int*)(ws + 208896);
    double* bll      = (double*)(ws + 215040);
    double* bpc      = (double*)(ws + 215552);
    int*    bnp      = (int*)(ws + 216064);
    float*  mine     = (float*)(ws + 262144);

    hipLaunchKernelGGL(kA_fused, dim3(NPB_, B_), dim3(256), 0, stream,
                       loc, conf, priors, truths, labels,
                       mine, part_ll, part_pce, part_np, part_key);
    hipLaunchKernelGGL(kB_batch, dim3(B_), dim3(1024), 0, stream,
                       loc, conf, priors, truths, labels, mine,
                       part_ll, part_pce, part_np, part_key, bll, bpc, bnp);
    hipLaunchKernelGGL(kC_final, dim3(1), dim3(64), 0, stream, bll, bpc, bnp, out);
}

// Round 5
// 332.038 us; speedup vs baseline: 1.2608x; 1.2608x over previous
//
#include <hip/hip_runtime.h>
#include <cstdint>
#include <cstddef>

#define B_ 64
#define P_ 24564
#define C_ 21
#define N_ 16
#define NPB_ 24          // kA blocks per batch: 24*1024 >= P_
#define THRESH_ 0.5f

// ---------------------------------------------------------------- helpers

__device__ inline unsigned long long shfl_down_u64(unsigned long long v, int off) {
    unsigned lo = (unsigned)v, hi = (unsigned)(v >> 32);
    lo = __shfl_down(lo, off);
    hi = __shfl_down(hi, off);
    return ((unsigned long long)hi << 32) | lo;
}

// smooth-L1 of (loc row - encoded(truth, prior)), summed over 4 coords
__device__ inline float sl1_encode(float4 ld, float4 pr,
                                   float tx1, float ty1, float tx2, float ty2) {
    float gcx = ((tx1 + tx2) * 0.5f - pr.x) / (0.1f * pr.z);
    float gcy = ((ty1 + ty2) * 0.5f - pr.y) / (0.1f * pr.w);
    float gw  = logf((tx2 - tx1) / pr.z) / 0.2f;
    float gh  = logf((ty2 - ty1) / pr.w) / 0.2f;
    float g[4] = {gcx, gcy, gw, gh};
    float l[4] = {ld.x, ld.y, ld.z, ld.w};
    float s = 0.0f;
#pragma unroll
    for (int i = 0; i < 4; i++) {
        float d = l[i] - g[i];
        float ad = fabsf(d);
        s += (ad < 1.0f) ? 0.5f * d * d : ad - 0.5f;
    }
    return s;
}

// ---------------------------------------------------------------- kernels

// kA: fused match + baseline loss (no override) + per-block best-prior
// argmax partials. Thread owns 4 consecutive priors (21 float4 conf loads,
// deep MLP). No global atomics. (unchanged from R3/R4 — 85 us, 893 GB/s)
__global__ __launch_bounds__(256) void
kA_fused(const float* __restrict__ loc,
         const float* __restrict__ conf,
         const float* __restrict__ priors,
         const float* __restrict__ truths,
         const int* __restrict__ labels,
         float* __restrict__ mine,
         float* __restrict__ part_ll,
         float* __restrict__ part_pce,
         int* __restrict__ part_np,
         unsigned long long* __restrict__ part_key) {
    int b = blockIdx.y, bx = blockIdx.x, t = threadIdx.x;
    __shared__ float tr[N_ * 4];
    __shared__ int lb[N_];
    __shared__ unsigned long long tmax[N_];
    if (t < N_ * 4) tr[t] = truths[b * N_ * 4 + t];
    if (t < N_) { lb[t] = labels[b * N_ + t]; tmax[t] = 0ull; }
    __syncthreads();

    int p0 = bx * 1024 + 4 * t;
    bool valid = p0 < P_;            // P_ % 4 == 0: all-or-nothing per thread
    int lane = t & 63;

    float c[84];
    if (valid) {
        const float4* src = (const float4*)(conf + ((size_t)b * P_ + (size_t)bx * 1024) * C_);
        float4* cv = (float4*)c;
#pragma unroll
        for (int i = 0; i < 21; i++) cv[i] = src[t * 21 + i];
    }

    float4 pr[4];
#pragma unroll
    for (int r = 0; r < 4; r++)
        pr[r] = valid ? ((const float4*)priors)[p0 + r]
                      : make_float4(0.5f, 0.5f, 0.1f, 0.1f);

    float px1[4], py1[4], px2[4], py2[4], ap[4];
#pragma unroll
    for (int r = 0; r < 4; r++) {
        px1[r] = pr[r].x - pr[r].z * 0.5f; py1[r] = pr[r].y - pr[r].w * 0.5f;
        px2[r] = pr[r].x + pr[r].z * 0.5f; py2[r] = pr[r].y + pr[r].w * 0.5f;
        ap[r] = (px2[r] - px1[r]) * (py2[r] - py1[r]);
    }

    float best[4] = {-1.0f, -1.0f, -1.0f, -1.0f};
    int bn[4] = {0, 0, 0, 0};

#pragma unroll
    for (int n = 0; n < N_; n++) {
        float tx1 = tr[n * 4 + 0], ty1 = tr[n * 4 + 1];
        float tx2 = tr[n * 4 + 2], ty2 = tr[n * 4 + 3];
        float at = (tx2 - tx1) * (ty2 - ty1);
        float tbi = -1.0f;
        int tbr = 0;
#pragma unroll
        for (int r = 0; r < 4; r++) {
            float lx = fmaxf(tx1, px1[r]), ly = fmaxf(ty1, py1[r]);
            float rx = fminf(tx2, px2[r]), ry = fminf(ty2, py2[r]);
            float w = fmaxf(rx - lx, 0.0f), h = fmaxf(ry - ly, 0.0f);
            float inter = w * h;
            float iou = inter / (at + ap[r] - inter);
            if (iou > best[r]) { best[r] = iou; bn[r] = n; }
            if (iou > tbi) { tbi = iou; tbr = r; }
        }
        unsigned long long key = valid
            ? (((unsigned long long)__float_as_uint(tbi) << 32) |
               (unsigned)~(unsigned)(p0 + tbr))
            : 0ull;
        for (int off = 32; off; off >>= 1) {
            unsigned long long o = shfl_down_u64(key, off);
            key = (o > key) ? o : key;
        }
        if (lane == 0) atomicMax(&tmax[n], key);
    }

    float ll = 0.0f, pce = 0.0f;
    int np = 0;
    if (valid) {
        float mv[4];
#pragma unroll
        for (int r = 0; r < 4; r++) {
            int bti = bn[r];
            int pos = (best[r] < THRESH_) ? 0 : 1;
            int cls = pos ? (lb[bti] + 1) : 0;

            float mx = -1e30f, g = 0.0f;
#pragma unroll
            for (int j = 0; j < C_; j++) {
                float x = c[21 * r + j];
                mx = fmaxf(mx, x);
                if (j == cls) g = x;
            }
            float s = 0.0f;
#pragma unroll
            for (int j = 0; j < C_; j++) s += expf(c[21 * r + j] - mx);
            float lca = mx + logf(s) - g;          // >= 0 always

            mv[r] = pos ? 0.0f : lca;
            if (pos) {
                np++;
                pce += lca;
                float4 ld = ((const float4*)loc)[(size_t)b * P_ + p0 + r];
                ll += sl1_encode(ld, pr[r], tr[bti * 4 + 0], tr[bti * 4 + 1],
                                 tr[bti * 4 + 2], tr[bti * 4 + 3]);
            }
        }
        *(float4*)(mine + (size_t)b * P_ + p0) = make_float4(mv[0], mv[1], mv[2], mv[3]);
    }

    for (int off = 32; off; off >>= 1) {
        ll += __shfl_down(ll, off);
        pce += __shfl_down(pce, off);
        np += __shfl_down(np, off);
    }
    __shared__ float sll[4], spc[4];
    __shared__ int snp[4];
    int wid = t >> 6;
    if (lane == 0) { sll[wid] = ll; spc[wid] = pce; snp[wid] = np; }
    __syncthreads();
    if (t == 0) {
        float a = 0.0f, cc = 0.0f;
        int q = 0;
        for (int i = 0; i < 4; i++) { a += sll[i]; cc += spc[i]; q += snp[i]; }
        part_ll[b * NPB_ + bx] = a;
        part_pce[b * NPB_ + bx] = cc;
        part_np[b * NPB_ + bx] = q;
    }
    if (t < N_) part_key[(size_t)(b * NPB_ + bx) * N_ + t] = tmax[t];
}

// kB: one block per batch. Reduce argmax partials -> bpi; exact override
// deltas for <=16 priors; top-k via radix select. Hot loops are
// register-resident: values cached once per thread, override patch is a
// per-thread register bitmask (thread t owns p == t mod 1024), histogram is
// one plain per-wave privatized LDS atomic per element.
__global__ __launch_bounds__(1024) void
kB_batch(const float* __restrict__ loc,
         const float* __restrict__ conf,
         const float* __restrict__ priors,
         const float* __restrict__ truths,
         const int* __restrict__ labels,
         const float* __restrict__ mine,
         const float* __restrict__ part_ll,
         const float* __restrict__ part_pce,
         const int* __restrict__ part_np,
         const unsigned long long* __restrict__ part_key,
         double* __restrict__ bll,
         double* __restrict__ bpc,
         int* __restrict__ bnp) {
    int b = blockIdx.x, t = threadIdx.x, wid = t >> 6, lane = t & 63;
    __shared__ float tr[N_ * 4];
    __shared__ int lb[N_];
    __shared__ int sp[N_];
    __shared__ int op[N_], on_[N_];
    __shared__ int sm;
    __shared__ float sdll, sdpce, sll_s, spc_s;
    __shared__ int sdnp, snp_s;
    __shared__ unsigned cnt[16 * 256];
    __shared__ unsigned spfx;
    __shared__ int skrem;
    __shared__ float wsum[16];

    if (t < N_ * 4) tr[t] = truths[b * N_ * 4 + t];
    if (t < N_) lb[t] = labels[b * N_ + t];
    if (t == 0) { sdll = 0.f; sdpce = 0.f; sdnp = 0; sll_s = 0.f; spc_s = 0.f; snp_s = 0; }
    if (t < N_) {                                  // phase 1: bpi reduce
        unsigned long long best = 0ull;
        for (int i = 0; i < NPB_; i++) {
            unsigned long long k = part_key[(size_t)(b * NPB_ + i) * N_ + t];
            best = (k > best) ? k : best;
        }
        sp[t] = (int)~(unsigned)(best & 0xFFFFFFFFull);
    }
    __syncthreads();
    if (t < NPB_) {                                // partial-sum gather
        atomicAdd(&sll_s, part_ll[b * NPB_ + t]);
        atomicAdd(&spc_s, part_pce[b * NPB_ + t]);
        atomicAdd(&snp_s, part_np[b * NPB_ + t]);
    }
    if (t == 0) {                                  // phase 2: dedup, last n wins
        int m = 0;
        for (int n = 0; n < N_; n++) {
            int p = sp[n], j;
            for (j = 0; j < m; j++) if (op[j] == p) { on_[j] = n; break; }
            if (j == m) { op[m] = p; on_[m] = n; m++; }
        }
        sm = m;
    }
    __syncthreads();
    int m = sm;
    if (t < m) {                                   // phase 3: exact deltas
        int p = op[t], nf = on_[t];
        float4 pr = ((const float4*)priors)[p];
        float px1 = pr.x - pr.z * 0.5f, py1 = pr.y - pr.w * 0.5f;
        float px2 = pr.x + pr.z * 0.5f, py2 = pr.y + pr.w * 0.5f;
        float ap = (px2 - px1) * (py2 - py1);
        float best = -1.0f;
        int bti = 0;
        for (int n = 0; n < N_; n++) {
            float tx1 = tr[n * 4], ty1 = tr[n * 4 + 1];
            float tx2 = tr[n * 4 + 2], ty2 = tr[n * 4 + 3];
            float at = (tx2 - tx1) * (ty2 - ty1);
            float lx = fmaxf(tx1, px1), ly = fmaxf(ty1, py1);
            float rx = fminf(tx2, px2), ry = fminf(ty2, py2);
            float w = fmaxf(rx - lx, 0.0f), h = fmaxf(ry - ly, 0.0f);
            float inter = w * h;
            float iou = inter / (at + ap - inter);
            if (iou > best) { best = iou; bti = n; }
        }
        int pos_old = (best >= THRESH_) ? 1 : 0;
        const float* cp = conf + ((size_t)b * P_ + p) * C_;
        float x[C_];
        float mx = -1e30f;
        for (int j = 0; j < C_; j++) { x[j] = cp[j]; mx = fmaxf(mx, x[j]); }
        float s = 0.0f;
        for (int j = 0; j < C_; j++) s += expf(x[j] - mx);
        float lse = mx + logf(s);
        float4 ld = ((const float4*)loc)[(size_t)b * P_ + p];
        float dll = sl1_encode(ld, pr, tr[nf * 4], tr[nf * 4 + 1],
                               tr[nf * 4 + 2], tr[nf * 4 + 3]);
        float dpce = lse - x[lb[nf] + 1];
        int dnp = 1 - pos_old;
        if (pos_old) {
            dll -= sl1_encode(ld, pr, tr[bti * 4], tr[bti * 4 + 1],
                              tr[bti * 4 + 2], tr[bti * 4 + 3]);
            dpce -= lse - x[lb[bti] + 1];
        }
        atomicAdd(&sdll, dll);
        atomicAdd(&sdpce, dpce);
        atomicAdd(&sdnp, dnp);
    }

    // ---- per-thread override bitmask + register-cached values ----
    // thread t owns priors p = t + 1024*i; override at op[j] belongs to
    // thread op[j]&1023, slot op[j]>>10. Overridden priors are positives ->
    // their mine value is exactly 0 (matches reference where(pos,0,...)).
    unsigned omask = 0;
    for (int j = 0; j < m; j++) {              // <=16 broadcast LDS reads, once
        int o = op[j];
        if ((o & 1023) == t) omask |= 1u << (o >> 10);
    }
    const float* v = mine + (size_t)b * P_;
    int nel = (t < (P_ - 23 * 1024)) ? 24 : 23;
    float xv[24];
#pragma unroll
    for (int i = 0; i < 24; i++) {
        float x = 0.0f;
        if (i < nel) x = v[t + (i << 10)];     // 24 independent L2 loads
        if ((omask >> i) & 1) x = 0.0f;
        xv[i] = x;
    }
    __syncthreads();                           // sdnp/snp_s complete
    int np = snp_s + sdnp;
    int k = np * 3;
    if (k > P_ - 1) k = P_ - 1;
    if (t == 0) { spfx = 0u; skrem = k; }

    for (int pass = 0; pass < 4; pass++) {
        for (int i2 = t; i2 < 16 * 256; i2 += 1024) cnt[i2] = 0u;
        __syncthreads();                       // also publishes spfx/skrem
        unsigned pf = spfx;
        unsigned pm = pass ? (0xFFFFFFFFu << (32 - 8 * pass)) : 0u;
        int shift = 24 - 8 * pass;
#pragma unroll
        for (int i = 0; i < 24; i++) {
            if (i < nel) {
                unsigned u = __float_as_uint(xv[i]);
                if ((u & pm) == pf)
                    atomicAdd(&cnt[(wid << 8) + ((u >> shift) & 255u)], 1u);
            }
        }
        __syncthreads();
        if (t < 256) {                         // fold 16 wave copies
            unsigned s2 = 0;
            for (int cc = 0; cc < 16; cc++) s2 += cnt[(cc << 8) + t];
            cnt[t] = s2;
        }
        __syncthreads();
        if (t == 0) {
            int kr = skrem;
            unsigned c2 = 0;
            int bin;
            for (bin = 255; bin >= 0; bin--) {
                if ((int)(c2 + cnt[bin]) >= kr) break;
                c2 += cnt[bin];
            }
            if (bin < 0) bin = 0;              // defensive
            skrem = kr - (int)c2;
            spfx = pf | ((unsigned)bin << shift);
        }
        __syncthreads();
    }

    unsigned thr = spfx;                       // exact k-th largest bit pattern
    float psum = 0.0f;
#pragma unroll
    for (int i = 0; i < 24; i++)
        if (i < nel && __float_as_uint(xv[i]) > thr) psum += xv[i];
    for (int off = 32; off; off >>= 1) psum += __shfl_down(psum, off);
    if (lane == 0) wsum[wid] = psum;
    __syncthreads();
    if (t == 0) {
        float s2 = 0.0f;
        for (int i = 0; i < 16; i++) s2 += wsum[i];
        double tot = (double)s2 + (double)skrem * (double)__uint_as_float(thr);
        bll[b] = (double)(sll_s + sdll);
        bpc[b] = (double)(spc_s + sdpce) + tot;
        bnp[b] = np;
    }
}

// kC: final 64-wide reduce.
__global__ void kC_final(const double* __restrict__ bll,
                         const double* __restrict__ bpc,
                         const int* __restrict__ bnp,
                         float* __restrict__ out) {
    int t = threadIdx.x;  // 64 threads
    double a = bll[t], c = bpc[t];
    int n = bnp[t];
    for (int off = 32; off; off >>= 1) {
        a += __shfl_down(a, off);
        c += __shfl_down(c, off);
        n += __shfl_down(n, off);
    }
    if (t == 0) {
        double dn = (double)n;
        out[0] = (float)(a / dn);
        out[1] = (float)(c / dn);
    }
}

// ---------------------------------------------------------------- launch

extern "C" void kernel_launch(void* const* d_in, const int* in_sizes, int n_in,
                              void* d_out, int out_size, void* d_ws, size_t ws_size,
                              hipStream_t stream) {
    const float* loc    = (const float*)d_in[0];
    const float* conf   = (const float*)d_in[1];
    const float* priors = (const float*)d_in[2];
    const float* truths = (const float*)d_in[3];
    const int*   labels = (const int*)d_in[4];
    float* out = (float*)d_out;

    char* ws = (char*)d_ws;
    unsigned long long* part_key = (unsigned long long*)(ws);
    float*  part_ll  = (float*)(ws + 196608);
    float*  part_pce = (float*)(ws + 202752);
    int*    part_np  = (int*)(ws + 208896);
    double* bll      = (double*)(ws + 215040);
    double* bpc      = (double*)(ws + 215552);
    int*    bnp      = (int*)(ws + 216064);
    float*  mine     = (float*)(ws + 262144);

    hipLaunchKernelGGL(kA_fused, dim3(NPB_, B_), dim3(256), 0, stream,
                       loc, conf, priors, truths, labels,
                       mine, part_ll, part_pce, part_np, part_key);
    hipLaunchKernelGGL(kB_batch, dim3(B_), dim3(1024), 0, stream,
                       loc, conf, priors, truths, labels, mine,
                       part_ll, part_pce, part_np, part_key, bll, bpc, bnp);
    hipLaunchKernelGGL(kC_final, dim3(1), dim3(64), 0, stream, bll, bpc, bnp, out);
}